// Round 2
// baseline (495.369 us; speedup 1.0000x reference)
//
#include <hip/hip_runtime.h>
#include <math.h>

// Problem constants (from reference)
#define HS    250      // sender hidden
#define HRr   100      // receiver hidden
#define VOC   40       // vocab, EOS = 39
#define TMAX  30       // max message length
#define NCLS  262144   // output classes
#define KS    10       // sender blocks (each owns 25 h-rows = 100 gate rows)
#define RPB   25       // h-rows per sender block

// ws layout (float indices). Total use ~WS_HR+128 floats (~9 KB) — exp values
// are staged directly in d_out to keep ws footprint tiny.
#define WS_FLAGS 0     // int flags[KS] : per-block step counters
#define WS_L     16    // int : message length
#define WS_SUM   17    // float : softmax denominator accumulator
#define WS_H0    64    // float[250]
#define WS_NH    320   // float[2][256] : double-buffered h exchange
#define WS_MSG   832   // float[30*40]
#define WS_HR    2048  // float[100] (byte offset 8192, 16B aligned)

__device__ __forceinline__ float sigf(float x) { return 1.f / (1.f + expf(-x)); }

// Wave-wide scalar broadcast of lane l's value (compile-time l) — forces
// v_readlane (VALU/scalar path) instead of ds_bpermute (LDS pipe).
__device__ __forceinline__ float lanebc(float v, int l) {
  return __int_as_float(__builtin_amdgcn_readlane(__float_as_int(v), l));
}

// ---------------- kernel 1: h0 = relu(W_s1 @ x + b_s1), 250x4096 ----------
__global__ __launch_bounds__(64) void k_h0(const float* __restrict__ x,
                                           const float* __restrict__ W,
                                           const float* __restrict__ b,
                                           float* __restrict__ ws) {
  const int row = blockIdx.x;        // 250
  const int l   = threadIdx.x;       // 64
  const float4* wr = (const float4*)(W + (size_t)row * 4096);
  const float4* xr = (const float4*)x;
  float ax = 0.f, ay = 0.f, az = 0.f, aw = 0.f;
  #pragma unroll 4
  for (int i = l; i < 1024; i += 64) {
    float4 w4 = wr[i], x4 = xr[i];
    ax += w4.x * x4.x; ay += w4.y * x4.y; az += w4.z * x4.z; aw += w4.w * x4.w;
  }
  float acc = (ax + ay) + (az + aw);
  #pragma unroll
  for (int o = 32; o; o >>= 1) acc += __shfl_down(acc, o);
  if (l == 0) ws[WS_H0 + row] = fmaxf(acc + b[row], 0.f);
}

// ---------------- kernel 2: sender LSTM, 10 flag-synced blocks -------------
// Thread map: wave w (8 waves of 512): part p = w&3 (k-slice of 64),
// local gate row lr = (w>>2)*64 + lane (active lr<100). Gate row lr = gi*25+rr
// -> global row gi*250 + b*25 + rr. Weights live in registers.
#define SENDER_GATES(P, HV)                                   \
  {                                                           \
    _Pragma("unroll")                                         \
    for (int i = 0; i < 64; i += 4) {                         \
      a0 += whh[i    ] * lanebc(HV, i    );                   \
      a1 += whh[i + 1] * lanebc(HV, i + 1);                   \
      a2 += whh[i + 2] * lanebc(HV, i + 2);                   \
      a3 += whh[i + 3] * lanebc(HV, i + 3);                   \
    }                                                         \
    _Pragma("unroll")                                         \
    for (int i = 0; i < 10; i += 2) {                         \
      a0 += wih[i    ] * lanebc(sv, (P) * 10 + i    );        \
      a1 += wih[i + 1] * lanebc(sv, (P) * 10 + i + 1);        \
    }                                                         \
  }

#define LOGIT_DOT(HV)                                         \
  {                                                           \
    _Pragma("unroll")                                         \
    for (int i = 0; i < 64; i += 4) {                         \
      a0 += wp[i    ] * lanebc(HV, i    );                    \
      a1 += wp[i + 1] * lanebc(HV, i + 1);                    \
      a2 += wp[i + 2] * lanebc(HV, i + 2);                    \
      a3 += wp[i + 3] * lanebc(HV, i + 3);                    \
    }                                                         \
  }

__global__ __launch_bounds__(512) void k_sender(
    const float* __restrict__ gum,
    const float* __restrict__ W_ih1, const float* __restrict__ W_hh1,
    const float* __restrict__ b_ih1, const float* __restrict__ b_hh1,
    const float* __restrict__ W_p,   const float* __restrict__ b_p,
    float* __restrict__ ws) {
  __shared__ float part[400];
  __shared__ float gate[100];
  __shared__ float part2[160];
  __shared__ float symL[VOC];
  __shared__ int   ctrl;

  const int b    = blockIdx.x;
  const int t0   = threadIdx.x;
  const int lane = t0 & 63;
  const int w    = t0 >> 6;
  const int p    = w & 3;
  const int lr   = ((w >> 2) << 6) + lane;   // 0..127
  const bool gact = (lr < 100);

  const int gi   = lr / 25, rr = lr % 25;
  const int grow = gi * 250 + b * RPB + rr;  // global gate row

  float whh[64], wih[10], bsum = 0.f;
  if (gact) {
    #pragma unroll
    for (int i = 0; i < 64; i++) {
      int k = p * 64 + i;
      whh[i] = (k < HS) ? W_hh1[(size_t)grow * HS + k] : 0.f;
    }
    #pragma unroll
    for (int i = 0; i < 10; i++) wih[i] = W_ih1[grow * VOC + p * 10 + i];
    bsum = b_ih1[grow] + b_hh1[grow];
  }
  // logits weights: waves 0..3, lane<40 -> logit j=lane, k-slice p*64..
  float wp[64];
  const bool lact = (w < 4) && (lane < VOC);
  if (lact) {
    #pragma unroll
    for (int i = 0; i < 64; i++) {
      int k = p * 64 + i;
      wp[i] = (k < HS) ? W_p[lane * HS + k] : 0.f;
    }
  }
  float bpv = 0.f;
  if (w == 0) bpv = b_p[lane < VOC ? lane : 0];

  // lane-distributed h (pad 250 -> 256 with zeros)
  float hv0 = ws[WS_H0 + lane];
  float hv1 = ws[WS_H0 + 64 + lane];
  float hv2 = ws[WS_H0 + 128 + lane];
  float hv3 = (192 + lane < HS) ? ws[WS_H0 + 192 + lane] : 0.f;
  float sv = 0.f;   // current symbol (sos = zeros), lane-distributed
  float c  = 0.f;   // cell state for threads t0<25 (row b*25+t0)

  int*   flags = (int*)ws;
  float* nh    = ws + WS_NH;
  float* msg   = ws + WS_MSG;

  for (int t = 0; t < TMAX; ++t) {
    // prefetch gumbel early (used far below in softmax phase)
    float gv = 0.f;
    if (w == 0) gv = gum[t * VOC + (lane < VOC ? lane : 0)];

    // ---- gates: 100 rows x (250 h + 40 sym), partials per p-slice ----
    if (gact) {
      float a0 = bsum, a1 = 0.f, a2 = 0.f, a3 = 0.f;
      if      (p == 0) SENDER_GATES(0, hv0)
      else if (p == 1) SENDER_GATES(1, hv1)
      else if (p == 2) SENDER_GATES(2, hv2)
      else             SENDER_GATES(3, hv3)
      part[p * 100 + lr] = (a0 + a1) + (a2 + a3);
    }
    __syncthreads();
    if (t0 < 100)
      gate[t0] = (part[t0] + part[100 + t0]) + (part[200 + t0] + part[300 + t0]);
    __syncthreads();

    // ---- h/c update for this block's 25 rows; publish nh slice ----
    if (t0 < RPB) {
      float ig = sigf(gate[t0]);
      float fg = sigf(gate[25 + t0]);
      float gg = tanhf(gate[50 + t0]);
      float og = sigf(gate[75 + t0]);
      float cn = fg * c + ig * gg;
      c = cn;
      float hn = og * tanhf(cn);
      __hip_atomic_store(&nh[(t & 1) * 256 + b * RPB + t0], hn,
                         __ATOMIC_RELEASE, __HIP_MEMORY_SCOPE_AGENT);
    }
    __syncthreads();  // drains all lanes' stores (vmcnt0 before s_barrier)
    if (t0 == 0)
      __hip_atomic_store(&flags[b], t + 1, __ATOMIC_RELEASE, __HIP_MEMORY_SCOPE_AGENT);
    if (t0 < KS) {    // parallel spin: thread o polls flag[o]
      while (__hip_atomic_load(&flags[t0], __ATOMIC_RELAXED,
                               __HIP_MEMORY_SCOPE_AGENT) < t + 1) {}
    }
    __syncthreads();
    __builtin_amdgcn_fence(__ATOMIC_ACQUIRE, "agent");

    // ---- reload full h (lane-distributed) from the exchange slot ----
    {
      const float* s = nh + (t & 1) * 256;
      hv0 = __hip_atomic_load(&s[lane],       __ATOMIC_ACQUIRE, __HIP_MEMORY_SCOPE_AGENT);
      hv1 = __hip_atomic_load(&s[64 + lane],  __ATOMIC_ACQUIRE, __HIP_MEMORY_SCOPE_AGENT);
      hv2 = __hip_atomic_load(&s[128 + lane], __ATOMIC_ACQUIRE, __HIP_MEMORY_SCOPE_AGENT);
      float x3 = __hip_atomic_load(&s[192 + lane], __ATOMIC_ACQUIRE, __HIP_MEMORY_SCOPE_AGENT);
      hv3 = (192 + lane < HS) ? x3 : 0.f;
    }

    // ---- logits = W_p @ nh (redundant per block) ----
    if (lact) {
      float a0 = 0.f, a1 = 0.f, a2 = 0.f, a3 = 0.f;
      if      (p == 0) LOGIT_DOT(hv0)
      else if (p == 1) LOGIT_DOT(hv1)
      else if (p == 2) LOGIT_DOT(hv2)
      else             LOGIT_DOT(hv3)
      part2[p * 40 + lane] = (a0 + a1) + (a2 + a3);
    }
    __syncthreads();

    // ---- gumbel-softmax / argmax / straight-through emit: wave 0 ----
    if (w == 0) {
      float lg = -INFINITY;
      if (lane < VOC)
        lg = ((bpv + gv) + (part2[lane] + part2[40 + lane]))
             + (part2[80 + lane] + part2[120 + lane]);
      float v = lg; int bi = lane;
      #pragma unroll
      for (int o = 32; o; o >>= 1) {        // first-max argmax (ties -> lower lane)
        float ov = __shfl_down(v, o);
        int   oi = __shfl_down(bi, o);
        if (ov > v) { v = ov; bi = oi; }
      }
      float m  = __shfl(v, 0);
      int  idx = __shfl(bi, 0);
      float e = (lane < VOC) ? expf(lg - m) : 0.f;
      float ssum = e;
      #pragma unroll
      for (int o = 32; o; o >>= 1) ssum += __shfl_down(ssum, o);
      ssum = __shfl(ssum, 0);
      float soft = e / ssum;
      float hard = (lane == idx) ? 1.f : 0.f;
      float st   = (hard + soft) - soft;           // exact ST forward ordering
      float emit = (t == TMAX - 1) ? ((lane == VOC - 1) ? 1.f : 0.f) : st;
      if (lane < VOC) {
        symL[lane] = emit;
        if (b == 0) msg[t * VOC + lane] = emit;
      }
      if (lane == 0) {
        int d = (idx == VOC - 1 || t == TMAX - 1) ? 1 : 0;
        ctrl = d;
        if (b == 0 && d) ((int*)ws)[WS_L] = t + 1;   // message length
      }
    }
    __syncthreads();
    sv = (lane < VOC) ? symL[lane] : 0.f;
    if (ctrl) break;   // deterministic & identical across blocks
  }
}

// ---------------- kernel 3: receiver LSTM, 1 block, weights in regs --------
__global__ __launch_bounds__(512) void k_recv(
    const float* __restrict__ W_ih2, const float* __restrict__ W_hh2,
    const float* __restrict__ b_ih2, const float* __restrict__ b_hh2,
    float* __restrict__ ws) {
  __shared__ float gL[400];
  __shared__ float hL[HRr];
  __shared__ int   Ls;
  const int t0   = threadIdx.x;
  const int lane = t0 & 63;
  const bool act = (t0 < 400);

  float wih[VOC], whh[HRr], bsum = 0.f;
  if (act) {
    #pragma unroll
    for (int i = 0; i < VOC; i++) wih[i] = W_ih2[t0 * VOC + i];
    #pragma unroll
    for (int i = 0; i < HRr; i++) whh[i] = W_hh2[t0 * HRr + i];
    bsum = b_ih2[t0] + b_hh2[t0];
  }
  if (t0 == 0) Ls = ((const int*)ws)[WS_L];
  __syncthreads();
  const int L = Ls;
  const float* msg = ws + WS_MSG;
  float c = 0.f, hv0 = 0.f, hv1 = 0.f;   // h lane-distributed: h[lane], h[64+lane]

  for (int t = 0; t < L; ++t) {
    float sv = (lane < VOC) ? msg[t * VOC + lane] : 0.f;
    if (act) {
      float a0 = bsum, a1 = 0.f, a2 = 0.f, a3 = 0.f;
      #pragma unroll
      for (int i = 0; i < VOC; i += 4) {
        a0 += wih[i    ] * lanebc(sv, i    );
        a1 += wih[i + 1] * lanebc(sv, i + 1);
        a2 += wih[i + 2] * lanebc(sv, i + 2);
        a3 += wih[i + 3] * lanebc(sv, i + 3);
      }
      #pragma unroll
      for (int i = 0; i < 64; i += 4) {
        a0 += whh[i    ] * lanebc(hv0, i    );
        a1 += whh[i + 1] * lanebc(hv0, i + 1);
        a2 += whh[i + 2] * lanebc(hv0, i + 2);
        a3 += whh[i + 3] * lanebc(hv0, i + 3);
      }
      #pragma unroll
      for (int i = 0; i < 36; i += 4) {
        a0 += whh[64 + i    ] * lanebc(hv1, i    );
        a1 += whh[64 + i + 1] * lanebc(hv1, i + 1);
        a2 += whh[64 + i + 2] * lanebc(hv1, i + 2);
        a3 += whh[64 + i + 3] * lanebc(hv1, i + 3);
      }
      gL[t0] = (a0 + a1) + (a2 + a3);
    }
    __syncthreads();
    if (t0 < HRr) {
      float ig = sigf(gL[t0]);
      float fg = sigf(gL[100 + t0]);
      float gg = tanhf(gL[200 + t0]);
      float og = sigf(gL[300 + t0]);
      float cn = fg * c + ig * gg; c = cn;
      hL[t0] = og * tanhf(cn);
    }
    __syncthreads();
    hv0 = hL[lane];                              // lane<64 < 100
    hv1 = (lane < 36) ? hL[64 + lane] : 0.f;
  }
  if (t0 < HRr) ws[WS_HR + t0] = hL[t0];
}

// ---------------- kernel 4: logits + exp + partial sum (105 MB HBM) --------
__global__ __launch_bounds__(256) void k_out(
    const float* __restrict__ W_r, const float* __restrict__ b_r,
    float* __restrict__ ws, float* __restrict__ out) {
  __shared__ float4 h4[25];
  __shared__ float  red[4];
  const int t0 = threadIdx.x;
  if (t0 < 25) h4[t0] = ((const float4*)(ws + WS_HR))[t0];
  __syncthreads();
  const int j = blockIdx.x * 256 + t0;
  const float4* wr = (const float4*)(W_r + (size_t)j * HRr);
  float ax = 0.f, ay = 0.f, az = 0.f, aw = 0.f;
  #pragma unroll
  for (int i = 0; i < 25; i++) {
    float4 wq = wr[i]; float4 hq = h4[i];
    ax += wq.x * hq.x; ay += wq.y * hq.y; az += wq.z * hq.z; aw += wq.w * hq.w;
  }
  float e = expf(((ax + ay) + (az + aw)) + b_r[j]);
  out[j] = e;
  float s = e;
  #pragma unroll
  for (int o = 32; o; o >>= 1) s += __shfl_down(s, o);
  if ((t0 & 63) == 0) red[t0 >> 6] = s;
  __syncthreads();
  if (t0 == 0) atomicAdd(&ws[WS_SUM], (red[0] + red[1]) + (red[2] + red[3]));
}

// ---------------- kernel 5: out *= 1/sum -----------------------------------
__global__ __launch_bounds__(256) void k_scale(const float* __restrict__ ws,
                                               float* __restrict__ out) {
  const float rinv = 1.f / ws[WS_SUM];
  const int i = blockIdx.x * 256 + threadIdx.x;   // float4 index
  float4 e = ((const float4*)out)[i];
  e.x *= rinv; e.y *= rinv; e.z *= rinv; e.w *= rinv;
  ((float4*)out)[i] = e;
}

extern "C" void kernel_launch(void* const* d_in, const int* in_sizes, int n_in,
                              void* d_out, int out_size, void* d_ws, size_t ws_size,
                              hipStream_t stream) {
  const float* x     = (const float*)d_in[0];
  const float* gum   = (const float*)d_in[1];
  const float* W_s1  = (const float*)d_in[2];
  const float* b_s1  = (const float*)d_in[3];
  const float* W_ih1 = (const float*)d_in[4];
  const float* W_hh1 = (const float*)d_in[5];
  const float* b_ih1 = (const float*)d_in[6];
  const float* b_hh1 = (const float*)d_in[7];
  const float* W_p   = (const float*)d_in[8];
  const float* b_p   = (const float*)d_in[9];
  const float* W_ih2 = (const float*)d_in[10];
  const float* W_hh2 = (const float*)d_in[11];
  const float* b_ih2 = (const float*)d_in[12];
  const float* b_hh2 = (const float*)d_in[13];
  const float* W_r   = (const float*)d_in[14];
  const float* b_r   = (const float*)d_in[15];
  float* ws  = (float*)d_ws;
  float* out = (float*)d_out;

  // zero flags / L / sum (ws is re-poisoned 0xAA before every launch)
  (void)hipMemsetAsync(d_ws, 0, 128, stream);
  k_h0    <<<250,       64, 0, stream>>>(x, W_s1, b_s1, ws);
  k_sender<<<KS,       512, 0, stream>>>(gum, W_ih1, W_hh1, b_ih1, b_hh1, W_p, b_p, ws);
  k_recv  <<<1,        512, 0, stream>>>(W_ih2, W_hh2, b_ih2, b_hh2, ws);
  k_out   <<<NCLS/256, 256, 0, stream>>>(W_r, b_r, ws, out);
  k_scale <<<NCLS/1024,256, 0, stream>>>(ws, out);
}

// Round 3
// 384.247 us; speedup vs baseline: 1.2892x; 1.2892x over previous
//
#include <hip/hip_runtime.h>
#include <math.h>

// Problem constants (from reference)
#define HS    250      // sender hidden
#define HRr   100      // receiver hidden
#define VOC   40       // vocab, EOS = 39
#define TMAX  30       // max message length
#define NCLS  262144   // output classes
#define KS    10       // sender blocks (each owns 25 h-rows = 100 gate rows)
#define RPB   25       // h-rows per sender block

// ws layout (float indices).
#define WS_FLAGS 0     // int flags[KS]
#define WS_L     16    // int : message length
#define WS_SUMS  64    // float[64] : softmax denominator partial slots
#define WS_H0    256   // float[250]
#define WS_NH    512   // float[2][256] : double-buffered h exchange
#define WS_MSG   1024  // float[30*40]
#define WS_HR    2304  // float[100] (byte offset 9216, 16B aligned)

__device__ __forceinline__ float sigf(float x) { return 1.f / (1.f + expf(-x)); }

// Wave-wide scalar broadcast of lane l's value (compile-time l) — v_readlane.
__device__ __forceinline__ float lanebc(float v, int l) {
  return __int_as_float(__builtin_amdgcn_readlane(__float_as_int(v), l));
}

// ---------------- kernel 1: h0 = relu(W_s1 @ x + b_s1), 250x4096 ----------
__global__ __launch_bounds__(64) void k_h0(const float* __restrict__ x,
                                           const float* __restrict__ W,
                                           const float* __restrict__ b,
                                           float* __restrict__ ws) {
  const int row = blockIdx.x;        // 250
  const int l   = threadIdx.x;       // 64
  const float4* wr = (const float4*)(W + (size_t)row * 4096);
  const float4* xr = (const float4*)x;
  float ax = 0.f, ay = 0.f, az = 0.f, aw = 0.f;
  #pragma unroll 4
  for (int i = l; i < 1024; i += 64) {
    float4 w4 = wr[i], x4 = xr[i];
    ax += w4.x * x4.x; ay += w4.y * x4.y; az += w4.z * x4.z; aw += w4.w * x4.w;
  }
  float acc = (ax + ay) + (az + aw);
  #pragma unroll
  for (int o = 32; o; o >>= 1) acc += __shfl_down(acc, o);
  if (l == 0) ws[WS_H0 + row] = fmaxf(acc + b[row], 0.f);
}

// ---------------- kernel 2: sender LSTM, 10 flag-synced blocks -------------
#define SENDER_GATES(P, HV)                                   \
  {                                                           \
    _Pragma("unroll")                                         \
    for (int i = 0; i < 64; i += 4) {                         \
      a0 += whh[i    ] * lanebc(HV, i    );                   \
      a1 += whh[i + 1] * lanebc(HV, i + 1);                   \
      a2 += whh[i + 2] * lanebc(HV, i + 2);                   \
      a3 += whh[i + 3] * lanebc(HV, i + 3);                   \
    }                                                         \
    _Pragma("unroll")                                         \
    for (int i = 0; i < 10; i += 2) {                         \
      a0 += wih[i    ] * lanebc(sv, (P) * 10 + i    );        \
      a1 += wih[i + 1] * lanebc(sv, (P) * 10 + i + 1);        \
    }                                                         \
  }

#define LOGIT_DOT(HV)                                         \
  {                                                           \
    _Pragma("unroll")                                         \
    for (int i = 0; i < 64; i += 4) {                         \
      a0 += wp[i    ] * lanebc(HV, i    );                    \
      a1 += wp[i + 1] * lanebc(HV, i + 1);                    \
      a2 += wp[i + 2] * lanebc(HV, i + 2);                    \
      a3 += wp[i + 3] * lanebc(HV, i + 3);                    \
    }                                                         \
  }

__global__ __launch_bounds__(512) void k_sender(
    const float* __restrict__ gum,
    const float* __restrict__ W_ih1, const float* __restrict__ W_hh1,
    const float* __restrict__ b_ih1, const float* __restrict__ b_hh1,
    const float* __restrict__ W_p,   const float* __restrict__ b_p,
    float* __restrict__ ws) {
  __shared__ float part[400];
  __shared__ float gate[100];
  __shared__ float part2[160];
  __shared__ float symL[VOC];
  __shared__ int   ctrl;

  const int b    = blockIdx.x;
  const int t0   = threadIdx.x;
  const int lane = t0 & 63;
  const int w    = t0 >> 6;
  const int p    = w & 3;
  const int lr   = ((w >> 2) << 6) + lane;   // 0..127
  const bool gact = (lr < 100);

  const int gi   = lr / 25, rr = lr % 25;
  const int grow = gi * 250 + b * RPB + rr;  // global gate row

  float whh[64], wih[10], bsum = 0.f;
  if (gact) {
    #pragma unroll
    for (int i = 0; i < 64; i++) {
      int k = p * 64 + i;
      whh[i] = (k < HS) ? W_hh1[(size_t)grow * HS + k] : 0.f;
    }
    #pragma unroll
    for (int i = 0; i < 10; i++) wih[i] = W_ih1[grow * VOC + p * 10 + i];
    bsum = b_ih1[grow] + b_hh1[grow];
  }
  float wp[64];
  const bool lact = (w < 4) && (lane < VOC);
  if (lact) {
    #pragma unroll
    for (int i = 0; i < 64; i++) {
      int k = p * 64 + i;
      wp[i] = (k < HS) ? W_p[lane * HS + k] : 0.f;
    }
  }
  float bpv = 0.f;
  if (w == 0) bpv = b_p[lane < VOC ? lane : 0];

  // lane-distributed h (pad 250 -> 256 with zeros)
  float hv0 = ws[WS_H0 + lane];
  float hv1 = ws[WS_H0 + 64 + lane];
  float hv2 = ws[WS_H0 + 128 + lane];
  float hv3 = (192 + lane < HS) ? ws[WS_H0 + 192 + lane] : 0.f;
  float sv = 0.f;   // current symbol (sos = zeros), lane-distributed
  float c  = 0.f;   // cell state for threads t0<25 (row b*25+t0)

  int*   flags = (int*)ws;
  float* nh    = ws + WS_NH;
  float* msg   = ws + WS_MSG;

  for (int t = 0; t < TMAX; ++t) {
    float gv = 0.f;
    if (w == 0) gv = gum[t * VOC + (lane < VOC ? lane : 0)];

    // ---- gates: 100 rows x (250 h + 40 sym), partials per p-slice ----
    if (gact) {
      float a0 = bsum, a1 = 0.f, a2 = 0.f, a3 = 0.f;
      if      (p == 0) SENDER_GATES(0, hv0)
      else if (p == 1) SENDER_GATES(1, hv1)
      else if (p == 2) SENDER_GATES(2, hv2)
      else             SENDER_GATES(3, hv3)
      part[p * 100 + lr] = (a0 + a1) + (a2 + a3);
    }
    __syncthreads();
    if (t0 < 100)
      gate[t0] = (part[t0] + part[100 + t0]) + (part[200 + t0] + part[300 + t0]);
    __syncthreads();

    // ---- h/c update for this block's 25 rows; publish nh slice ----
    // RELAXED agent stores: sc1, serviced at the coherence point, no
    // per-instruction cache maintenance. Visibility chain: these stores
    // happen-before the barrier, barrier happens-before t0==0's RELEASE
    // flag store, which publishes all HB-prior writes.
    if (t0 < RPB) {
      float ig = sigf(gate[t0]);
      float fg = sigf(gate[25 + t0]);
      float gg = tanhf(gate[50 + t0]);
      float og = sigf(gate[75 + t0]);
      float cn = fg * c + ig * gg;
      c = cn;
      float hn = og * tanhf(cn);
      __hip_atomic_store(&nh[(t & 1) * 256 + b * RPB + t0], hn,
                         __ATOMIC_RELAXED, __HIP_MEMORY_SCOPE_AGENT);
    }
    __syncthreads();
    if (t0 == 0)
      __hip_atomic_store(&flags[b], t + 1, __ATOMIC_RELEASE, __HIP_MEMORY_SCOPE_AGENT);
    if (t0 < KS) {    // parallel spin: thread o polls flag[o]
      while (__hip_atomic_load(&flags[t0], __ATOMIC_RELAXED,
                               __HIP_MEMORY_SCOPE_AGENT) < t + 1) {}
    }
    __syncthreads();
    // ONE acquire fence per step instead of per-load acquire semantics.
    __builtin_amdgcn_fence(__ATOMIC_ACQUIRE, "agent");

    // ---- reload full h (lane-distributed), RELAXED sc1 loads ----
    {
      const float* s = nh + (t & 1) * 256;
      hv0 = __hip_atomic_load(&s[lane],       __ATOMIC_RELAXED, __HIP_MEMORY_SCOPE_AGENT);
      hv1 = __hip_atomic_load(&s[64 + lane],  __ATOMIC_RELAXED, __HIP_MEMORY_SCOPE_AGENT);
      hv2 = __hip_atomic_load(&s[128 + lane], __ATOMIC_RELAXED, __HIP_MEMORY_SCOPE_AGENT);
      float x3 = __hip_atomic_load(&s[192 + lane], __ATOMIC_RELAXED, __HIP_MEMORY_SCOPE_AGENT);
      hv3 = (192 + lane < HS) ? x3 : 0.f;
    }

    // ---- logits = W_p @ nh (redundant per block) ----
    if (lact) {
      float a0 = 0.f, a1 = 0.f, a2 = 0.f, a3 = 0.f;
      if      (p == 0) LOGIT_DOT(hv0)
      else if (p == 1) LOGIT_DOT(hv1)
      else if (p == 2) LOGIT_DOT(hv2)
      else             LOGIT_DOT(hv3)
      part2[p * 40 + lane] = (a0 + a1) + (a2 + a3);
    }
    __syncthreads();

    // ---- gumbel-softmax / argmax / straight-through emit: wave 0 ----
    if (w == 0) {
      float lg = -INFINITY;
      if (lane < VOC)
        lg = ((bpv + gv) + (part2[lane] + part2[40 + lane]))
             + (part2[80 + lane] + part2[120 + lane]);
      float v = lg; int bi = lane;
      #pragma unroll
      for (int o = 32; o; o >>= 1) {        // first-max argmax (ties -> lower lane)
        float ov = __shfl_down(v, o);
        int   oi = __shfl_down(bi, o);
        if (ov > v) { v = ov; bi = oi; }
      }
      float m  = __shfl(v, 0);
      int  idx = __shfl(bi, 0);
      float e = (lane < VOC) ? expf(lg - m) : 0.f;
      float ssum = e;
      #pragma unroll
      for (int o = 32; o; o >>= 1) ssum += __shfl_down(ssum, o);
      ssum = __shfl(ssum, 0);
      float soft = e / ssum;
      float hard = (lane == idx) ? 1.f : 0.f;
      float st   = (hard + soft) - soft;           // exact ST forward ordering
      float emit = (t == TMAX - 1) ? ((lane == VOC - 1) ? 1.f : 0.f) : st;
      if (lane < VOC) {
        symL[lane] = emit;
        if (b == 0) msg[t * VOC + lane] = emit;
      }
      if (lane == 0) {
        int d = (idx == VOC - 1 || t == TMAX - 1) ? 1 : 0;
        ctrl = d;
        if (b == 0 && d) ((int*)ws)[WS_L] = t + 1;   // message length
      }
    }
    __syncthreads();
    sv = (lane < VOC) ? symL[lane] : 0.f;
    if (ctrl) break;   // deterministic & identical across blocks
  }
}

// ---------------- kernel 3: receiver LSTM, 1 block, weights in regs --------
__global__ __launch_bounds__(512) void k_recv(
    const float* __restrict__ W_ih2, const float* __restrict__ W_hh2,
    const float* __restrict__ b_ih2, const float* __restrict__ b_hh2,
    float* __restrict__ ws) {
  __shared__ float gL[400];
  __shared__ float hL[HRr];
  __shared__ int   Ls;
  const int t0   = threadIdx.x;
  const int lane = t0 & 63;
  const bool act = (t0 < 400);

  float wih[VOC], whh[HRr], bsum = 0.f;
  if (act) {
    #pragma unroll
    for (int i = 0; i < VOC; i++) wih[i] = W_ih2[t0 * VOC + i];
    #pragma unroll
    for (int i = 0; i < HRr; i++) whh[i] = W_hh2[t0 * HRr + i];
    bsum = b_ih2[t0] + b_hh2[t0];
  }
  if (t0 == 0) Ls = ((const int*)ws)[WS_L];
  __syncthreads();
  const int L = Ls;
  const float* msg = ws + WS_MSG;
  float c = 0.f, hv0 = 0.f, hv1 = 0.f;

  for (int t = 0; t < L; ++t) {
    float sv = (lane < VOC) ? msg[t * VOC + lane] : 0.f;
    if (act) {
      float a0 = bsum, a1 = 0.f, a2 = 0.f, a3 = 0.f;
      #pragma unroll
      for (int i = 0; i < VOC; i += 4) {
        a0 += wih[i    ] * lanebc(sv, i    );
        a1 += wih[i + 1] * lanebc(sv, i + 1);
        a2 += wih[i + 2] * lanebc(sv, i + 2);
        a3 += wih[i + 3] * lanebc(sv, i + 3);
      }
      #pragma unroll
      for (int i = 0; i < 64; i += 4) {
        a0 += whh[i    ] * lanebc(hv0, i    );
        a1 += whh[i + 1] * lanebc(hv0, i + 1);
        a2 += whh[i + 2] * lanebc(hv0, i + 2);
        a3 += whh[i + 3] * lanebc(hv0, i + 3);
      }
      #pragma unroll
      for (int i = 0; i < 36; i += 4) {
        a0 += whh[64 + i    ] * lanebc(hv1, i    );
        a1 += whh[64 + i + 1] * lanebc(hv1, i + 1);
        a2 += whh[64 + i + 2] * lanebc(hv1, i + 2);
        a3 += whh[64 + i + 3] * lanebc(hv1, i + 3);
      }
      gL[t0] = (a0 + a1) + (a2 + a3);
    }
    __syncthreads();
    if (t0 < HRr) {
      float ig = sigf(gL[t0]);
      float fg = sigf(gL[100 + t0]);
      float gg = tanhf(gL[200 + t0]);
      float og = sigf(gL[300 + t0]);
      float cn = fg * c + ig * gg; c = cn;
      hL[t0] = og * tanhf(cn);
    }
    __syncthreads();
    hv0 = hL[lane];
    hv1 = (lane < 36) ? hL[64 + lane] : 0.f;
  }
  if (t0 < HRr) ws[WS_HR + t0] = hL[t0];
}

// ---------------- kernel 4: logits + exp + partial sums (105 MB HBM) -------
// Coalesced: 4 lanes per row; lane 4k+c reads float4 chunks c, c+4, ... of
// row k -> consecutive lanes hit consecutive 16B chunks (~16 lines per
// wave-load instead of 64). shfl_xor reduces the 4 partials.
__global__ __launch_bounds__(256) void k_out(
    const float* __restrict__ W_r, const float* __restrict__ b_r,
    float* __restrict__ ws, float* __restrict__ out) {
  __shared__ float4 h4[25];
  __shared__ float  red[4];
  const int t0 = threadIdx.x;
  if (t0 < 25) h4[t0] = ((const float4*)(ws + WS_HR))[t0];
  __syncthreads();
  const int lane = t0 & 63;
  const int wv   = t0 >> 6;
  const int c0   = lane & 3;
  const int row  = (blockIdx.x << 6) + (wv << 4) + (lane >> 2);  // 64 rows/block
  const float4* wr = (const float4*)(W_r + (size_t)row * HRr);
  float acc = 0.f;
  #pragma unroll
  for (int j = 0; j < 7; ++j) {
    int ch = 4 * j + c0;
    if (ch < 25) {
      float4 w4 = wr[ch]; float4 hq = h4[ch];
      acc += w4.x * hq.x + w4.y * hq.y + w4.z * hq.z + w4.w * hq.w;
    }
  }
  acc += __shfl_xor(acc, 1);
  acc += __shfl_xor(acc, 2);           // all 4 lanes: full row dot
  float e = expf(acc + b_r[row]);
  if (c0 == 0) out[row] = e;           // 16 lanes -> 64B contiguous store
  float es = (c0 == 0) ? e : 0.f;
  #pragma unroll
  for (int o = 32; o; o >>= 1) es += __shfl_down(es, o);
  if (lane == 0) red[wv] = es;
  __syncthreads();
  if (t0 == 0)
    atomicAdd(&ws[WS_SUMS + (blockIdx.x & 63)], (red[0] + red[1]) + (red[2] + red[3]));
}

// ---------------- kernel 5: out *= 1/sum -----------------------------------
__global__ __launch_bounds__(256) void k_scale(const float* __restrict__ ws,
                                               float* __restrict__ out) {
  float s = ws[WS_SUMS + (threadIdx.x & 63)];
  #pragma unroll
  for (int o = 1; o < 64; o <<= 1) s += __shfl_xor(s, o);   // identical all lanes
  const float rinv = 1.f / s;
  const int i = blockIdx.x * 256 + threadIdx.x;   // float4 index
  float4 e = ((const float4*)out)[i];
  e.x *= rinv; e.y *= rinv; e.z *= rinv; e.w *= rinv;
  ((float4*)out)[i] = e;
}

extern "C" void kernel_launch(void* const* d_in, const int* in_sizes, int n_in,
                              void* d_out, int out_size, void* d_ws, size_t ws_size,
                              hipStream_t stream) {
  const float* x     = (const float*)d_in[0];
  const float* gum   = (const float*)d_in[1];
  const float* W_s1  = (const float*)d_in[2];
  const float* b_s1  = (const float*)d_in[3];
  const float* W_ih1 = (const float*)d_in[4];
  const float* W_hh1 = (const float*)d_in[5];
  const float* b_ih1 = (const float*)d_in[6];
  const float* b_hh1 = (const float*)d_in[7];
  const float* W_p   = (const float*)d_in[8];
  const float* b_p   = (const float*)d_in[9];
  const float* W_ih2 = (const float*)d_in[10];
  const float* W_hh2 = (const float*)d_in[11];
  const float* b_ih2 = (const float*)d_in[12];
  const float* b_hh2 = (const float*)d_in[13];
  const float* W_r   = (const float*)d_in[14];
  const float* b_r   = (const float*)d_in[15];
  float* ws  = (float*)d_ws;
  float* out = (float*)d_out;

  // zero flags / L / sum slots (ws is re-poisoned 0xAA before every launch)
  (void)hipMemsetAsync(d_ws, 0, 512, stream);
  k_h0    <<<250,       64, 0, stream>>>(x, W_s1, b_s1, ws);
  k_sender<<<KS,       512, 0, stream>>>(gum, W_ih1, W_hh1, b_ih1, b_hh1, W_p, b_p, ws);
  k_recv  <<<1,        512, 0, stream>>>(W_ih2, W_hh2, b_ih2, b_hh2, ws);
  k_out   <<<NCLS/64,  256, 0, stream>>>(W_r, b_r, ws, out);
  k_scale <<<NCLS/1024,256, 0, stream>>>(ws, out);
}

// Round 4
// 323.202 us; speedup vs baseline: 1.5327x; 1.1889x over previous
//
#include <hip/hip_runtime.h>
#include <math.h>

// Problem constants (from reference)
#define HS    250      // sender hidden
#define HRr   100      // receiver hidden
#define VOC   40       // vocab, EOS = 39
#define TMAX  30       // max message length
#define NCLS  262144   // output classes
#define KS    10       // sender blocks (each owns 25 h-rows = 100 gate rows)
#define RPB   25       // h-rows per sender block

// ws layout (float indices)
#define WS_FLAGS 0     // int[10] : per-block step counters
#define WS_MFLAG 32    // int : message flag, (step+1) | (done<<16)
#define WS_SUMS  64    // float[64] : softmax denominator partial slots
#define WS_NH    448   // float[2][256] : double-buffered h exchange
#define WS_LP    960   // float[2][10*40] : logit partials per block
#define WS_MSG   1792  // float[30*40]
#define WS_HR    3008  // float[100] (byte 12032, 16B aligned)

#define ATOMIC_ST_REL(p, v) __hip_atomic_store((p), (v), __ATOMIC_RELEASE, __HIP_MEMORY_SCOPE_AGENT)
#define ATOMIC_ST_RLX(p, v) __hip_atomic_store((p), (v), __ATOMIC_RELAXED, __HIP_MEMORY_SCOPE_AGENT)
#define ATOMIC_LD_RLX(p)    __hip_atomic_load((p), __ATOMIC_RELAXED, __HIP_MEMORY_SCOPE_AGENT)

__device__ __forceinline__ float sigf(float x) { return 1.f / (1.f + expf(-x)); }

// Wave-wide scalar broadcast of lane l's value (compile-time l) — v_readlane.
__device__ __forceinline__ float lanebc(float v, int l) {
  return __int_as_float(__builtin_amdgcn_readlane(__float_as_int(v), l));
}

#define SENDER_GATES(P, HV)                                   \
  {                                                           \
    _Pragma("unroll")                                         \
    for (int i = 0; i < 64; i += 4) {                         \
      a0 += whh[i    ] * lanebc(HV, i    );                   \
      a1 += whh[i + 1] * lanebc(HV, i + 1);                   \
      a2 += whh[i + 2] * lanebc(HV, i + 2);                   \
      a3 += whh[i + 3] * lanebc(HV, i + 3);                   \
    }                                                         \
    _Pragma("unroll")                                         \
    for (int i = 0; i < 10; i += 2) {                         \
      a0 += wih[i    ] * lanebc(sv, (P) * 10 + i    );        \
      a1 += wih[i + 1] * lanebc(sv, (P) * 10 + i + 1);        \
    }                                                         \
  }

// Reduce the 4 k-slice partials for gate row x (same pairing as before).
#define RED(x) ((part[(x)] + part[100 + (x)]) + (part[200 + (x)] + part[300 + (x)]))

// Wave-0 spin until all KS flags >= need.
#define SPIN_FLAGS(need_)                                                     \
  {                                                                           \
    int v;                                                                    \
    do {                                                                      \
      v = (lane < KS) ? ATOMIC_LD_RLX(&flags[lane]) : (need_);                \
    } while (!__all(v >= (need_)));                                           \
  }

// ---------------- fused kernel: h0 + sender LSTM (blocks 0..9) +
//                  receiver LSTM (block 10, concurrent consumer) ------------
__global__ __launch_bounds__(512, 2) void k_sender(
    const float* __restrict__ x,
    const float* __restrict__ W_s1,  const float* __restrict__ b_s1,
    const float* __restrict__ gum,
    const float* __restrict__ W_ih1, const float* __restrict__ W_hh1,
    const float* __restrict__ b_ih1, const float* __restrict__ b_hh1,
    const float* __restrict__ W_p,   const float* __restrict__ b_p,
    const float* __restrict__ W_ih2, const float* __restrict__ W_hh2,
    const float* __restrict__ b_ih2, const float* __restrict__ b_hh2,
    float* __restrict__ ws) {
  __shared__ float part[512];   // padded: wave0 reduce reads up to idx 438
  __shared__ float symL[VOC];
  __shared__ float h0L[32];
  __shared__ int   ctrl;
  __shared__ float gL[400];     // receiver
  __shared__ float hL[HRr];     // receiver
  __shared__ int   rawL;        // receiver

  const int b    = blockIdx.x;
  const int t0   = threadIdx.x;
  const int lane = t0 & 63;
  const int w    = t0 >> 6;

  int*   flags = (int*)ws;
  int*   mflag = (int*)ws + WS_MFLAG;
  float* nh    = ws + WS_NH;
  float* lp    = ws + WS_LP;
  float* msg   = ws + WS_MSG;

  if (b < KS) {
    // ================= SENDER =================
    const int p    = w & 3;
    const int lr   = ((w >> 2) << 6) + lane;   // 0..127
    const bool gact = (lr < 100);
    const int gi   = lr / 25, rr = lr % 25;
    const int grow = gi * 250 + b * RPB + rr;  // global gate row

    float whh[64], wih[10], bsum = 0.f;
    if (gact) {
      #pragma unroll
      for (int i = 0; i < 64; i++) {
        int k = p * 64 + i;
        whh[i] = (k < HS) ? W_hh1[(size_t)grow * HS + k] : 0.f;
      }
      #pragma unroll
      for (int i = 0; i < 10; i++) wih[i] = W_ih1[grow * VOC + p * 10 + i];
      bsum = b_ih1[grow] + b_hh1[grow];
    }
    // wave 0: W_p slice (lane j holds W_p[j, b*25 .. +25)), bias
    float wps[RPB];
    float bpv = 0.f;
    if (w == 0) {
      #pragma unroll
      for (int r = 0; r < RPB; r++)
        wps[r] = (lane < VOC) ? W_p[lane * HS + b * RPB + r] : 0.f;
      bpv = (lane < VOC) ? b_p[lane] : 0.f;
    }

    // ---- pre-step: h0 = relu(W_s1 @ x + b_s1), this block's 25 rows ----
    {
      const int nr = (w == 7) ? 4 : 3;         // rows 3w..3w+2 (+row 24 on w7)
      for (int j = 0; j < nr; ++j) {
        const int r = 3 * w + j;
        const float4* wr = (const float4*)(W_s1 + (size_t)(b * RPB + r) * 4096);
        const float4* xr = (const float4*)x;
        float a0 = 0.f, a1 = 0.f, a2 = 0.f, a3 = 0.f;
        #pragma unroll
        for (int q = 0; q < 16; ++q) {
          float4 w4 = wr[lane + (q << 6)], x4 = xr[lane + (q << 6)];
          a0 += w4.x * x4.x; a1 += w4.y * x4.y; a2 += w4.z * x4.z; a3 += w4.w * x4.w;
        }
        float acc = (a0 + a1) + (a2 + a3);
        #pragma unroll
        for (int o = 32; o; o >>= 1) acc += __shfl_down(acc, o);
        if (lane == 0) h0L[r] = acc + b_s1[b * RPB + r];
      }
    }
    __syncthreads();
    if (w == 0) {
      float hn0 = fmaxf(h0L[lane < RPB ? lane : 0], 0.f);
      if (lane < RPB) ATOMIC_ST_RLX(&nh[b * RPB + lane], hn0);  // slot 0
      if (lane == 0)  ATOMIC_ST_REL(&flags[b], 1);
      SPIN_FLAGS(1)
    }
    __syncthreads();

    float hv0, hv1, hv2, hv3;
    {
      const float* sl = nh;                    // slot 0
      hv0 = ATOMIC_LD_RLX(&sl[lane]);
      hv1 = ATOMIC_LD_RLX(&sl[64 + lane]);
      hv2 = ATOMIC_LD_RLX(&sl[128 + lane]);
      float x3 = ATOMIC_LD_RLX(&sl[192 + lane]);
      hv3 = (192 + lane < HS) ? x3 : 0.f;
    }
    float sv = 0.f;   // sos
    float c  = 0.f;   // cell state, wave0 lanes<25

    for (int s = 0; s < TMAX; ++s) {
      const int parity = (s + 1) & 1;
      float gv = 0.f;
      if (w == 0) gv = gum[s * VOC + (lane < VOC ? lane : 0)];

      // ---- gate partials: 100 rows x k-slice, all 8 waves ----
      if (gact) {
        float a0 = bsum, a1 = 0.f, a2 = 0.f, a3 = 0.f;
        if      (p == 0) SENDER_GATES(0, hv0)
        else if (p == 1) SENDER_GATES(1, hv1)
        else if (p == 2) SENDER_GATES(2, hv2)
        else             SENDER_GATES(3, hv3)
        part[p * 100 + lr] = (a0 + a1) + (a2 + a3);
      }
      __syncthreads();   // #1

      // ---- wave-0 fast path: reduce, h/c, logit partial, publish ----
      if (w == 0) {
        float gi_ = RED(lane);
        float gf_ = RED(25 + lane);
        float gg_ = RED(50 + lane);
        float go_ = RED(75 + lane);
        float ig = sigf(gi_), fg = sigf(gf_), gg = tanhf(gg_), og = sigf(go_);
        float cn = fg * c + ig * gg; c = cn;          // lanes>=25: garbage, unused
        float hn = og * tanhf(cn);
        float lpv = 0.f;
        #pragma unroll
        for (int r = 0; r < RPB; ++r) lpv += wps[r] * lanebc(hn, r);
        float* slot = nh + parity * 256;
        float* lps  = lp + parity * 400;
        if (lane < RPB) ATOMIC_ST_RLX(&slot[b * RPB + lane], hn);
        if (lane < VOC) ATOMIC_ST_RLX(&lps[b * VOC + lane], lpv);
        if (lane == 0)  ATOMIC_ST_REL(&flags[b], s + 2);
        SPIN_FLAGS(s + 2)
      }
      __syncthreads();   // #2

      // ---- gather h(s+1), all waves ----
      {
        const float* sl = nh + parity * 256;
        hv0 = ATOMIC_LD_RLX(&sl[lane]);
        hv1 = ATOMIC_LD_RLX(&sl[64 + lane]);
        hv2 = ATOMIC_LD_RLX(&sl[128 + lane]);
        float x3 = ATOMIC_LD_RLX(&sl[192 + lane]);
        hv3 = (192 + lane < HS) ? x3 : 0.f;
      }

      // ---- wave 0: sum logit partials, gumbel softmax, emit ----
      if (w == 0) {
        float lg = -INFINITY;
        if (lane < VOC) {
          float acc = bpv + gv;
          const float* ls = lp + parity * 400;
          #pragma unroll
          for (int j = 0; j < KS; ++j) acc += ATOMIC_LD_RLX(&ls[j * VOC + lane]);
          lg = acc;
        }
        float v = lg; int bi = lane;
        #pragma unroll
        for (int o = 32; o; o >>= 1) {      // first-max argmax (ties -> lower lane)
          float ov = __shfl_down(v, o);
          int   oi = __shfl_down(bi, o);
          if (ov > v) { v = ov; bi = oi; }
        }
        float m  = __shfl(v, 0);
        int  idx = __shfl(bi, 0);
        float e = (lane < VOC) ? expf(lg - m) : 0.f;
        float ssum = e;
        #pragma unroll
        for (int o = 32; o; o >>= 1) ssum += __shfl_down(ssum, o);
        ssum = __shfl(ssum, 0);
        float soft = e / ssum;
        float hard = (lane == idx) ? 1.f : 0.f;
        float st   = (hard + soft) - soft;           // exact ST forward ordering
        float emit = (s == TMAX - 1) ? ((lane == VOC - 1) ? 1.f : 0.f) : st;
        if (lane < VOC) {
          symL[lane] = emit;
          if (b == 0) ATOMIC_ST_RLX(&msg[s * VOC + lane], emit);
        }
        if (lane == 0) {
          int d = (idx == VOC - 1 || s == TMAX - 1) ? 1 : 0;
          ctrl = d;
          if (b == 0) ATOMIC_ST_REL(mflag, (s + 1) | (d << 16));
        }
      }
      __syncthreads();   // #3
      sv = (lane < VOC) ? symL[lane] : 0.f;
      if (ctrl) break;   // deterministic & identical across blocks
    }
  } else {
    // ================= RECEIVER (concurrent consumer) =================
    const bool act = (t0 < 400);
    float wih2[VOC], whh2[HRr], bsum2 = 0.f;
    if (act) {
      #pragma unroll
      for (int i = 0; i < VOC; i++) wih2[i] = W_ih2[t0 * VOC + i];
      #pragma unroll
      for (int i = 0; i < HRr; i++) whh2[i] = W_hh2[t0 * HRr + i];
      bsum2 = b_ih2[t0] + b_hh2[t0];
    }
    float c2 = 0.f, rv0 = 0.f, rv1 = 0.f;

    for (int t = 0; t < TMAX; ++t) {
      if (w == 0) {
        int raw;
        do { raw = ATOMIC_LD_RLX(mflag); } while ((raw & 0xFFFF) < t + 1);
        if (lane == 0) rawL = raw;
      }
      __syncthreads();
      const int raw = rawL;
      float sv2 = (lane < VOC) ? ATOMIC_LD_RLX(&msg[t * VOC + lane]) : 0.f;
      if (act) {
        float a0 = bsum2, a1 = 0.f, a2 = 0.f, a3 = 0.f;
        #pragma unroll
        for (int i = 0; i < VOC; i += 4) {
          a0 += wih2[i    ] * lanebc(sv2, i    );
          a1 += wih2[i + 1] * lanebc(sv2, i + 1);
          a2 += wih2[i + 2] * lanebc(sv2, i + 2);
          a3 += wih2[i + 3] * lanebc(sv2, i + 3);
        }
        #pragma unroll
        for (int i = 0; i < 64; i += 4) {
          a0 += whh2[i    ] * lanebc(rv0, i    );
          a1 += whh2[i + 1] * lanebc(rv0, i + 1);
          a2 += whh2[i + 2] * lanebc(rv0, i + 2);
          a3 += whh2[i + 3] * lanebc(rv0, i + 3);
        }
        #pragma unroll
        for (int i = 0; i < 36; i += 4) {
          a0 += whh2[64 + i    ] * lanebc(rv1, i    );
          a1 += whh2[64 + i + 1] * lanebc(rv1, i + 1);
          a2 += whh2[64 + i + 2] * lanebc(rv1, i + 2);
          a3 += whh2[64 + i + 3] * lanebc(rv1, i + 3);
        }
        gL[t0] = (a0 + a1) + (a2 + a3);
      }
      __syncthreads();
      if (t0 < HRr) {
        float ig = sigf(gL[t0]);
        float fg = sigf(gL[100 + t0]);
        float gg = tanhf(gL[200 + t0]);
        float og = sigf(gL[300 + t0]);
        float cn = fg * c2 + ig * gg; c2 = cn;
        hL[t0] = og * tanhf(cn);
      }
      __syncthreads();
      rv0 = hL[lane];
      rv1 = (lane < 36) ? hL[64 + lane] : 0.f;
      if ((raw >> 16) != 0 && (raw & 0xFFFF) == t + 1) break;
    }
    if (t0 < HRr) ws[WS_HR + t0] = hL[t0];
  }
}

// ---------------- kernel 2: logits + exp + partial sums (105 MB HBM) -------
__global__ __launch_bounds__(256) void k_out(
    const float* __restrict__ W_r, const float* __restrict__ b_r,
    float* __restrict__ ws, float* __restrict__ out) {
  __shared__ float4 h4[25];
  __shared__ float  red[4];
  const int t0 = threadIdx.x;
  if (t0 < 25) h4[t0] = ((const float4*)(ws + WS_HR))[t0];
  __syncthreads();
  const int lane = t0 & 63;
  const int wv   = t0 >> 6;
  const int c0   = lane & 3;
  const int row  = (blockIdx.x << 6) + (wv << 4) + (lane >> 2);  // 64 rows/block
  const float4* wr = (const float4*)(W_r + (size_t)row * HRr);
  float acc = 0.f;
  #pragma unroll
  for (int j = 0; j < 7; ++j) {
    int ch = 4 * j + c0;
    if (ch < 25) {
      float4 w4 = wr[ch]; float4 hq = h4[ch];
      acc += w4.x * hq.x + w4.y * hq.y + w4.z * hq.z + w4.w * hq.w;
    }
  }
  acc += __shfl_xor(acc, 1);
  acc += __shfl_xor(acc, 2);           // all 4 lanes: full row dot
  float e = expf(acc + b_r[row]);
  if (c0 == 0) out[row] = e;           // 16 lanes -> 64B contiguous store
  float es = (c0 == 0) ? e : 0.f;
  #pragma unroll
  for (int o = 32; o; o >>= 1) es += __shfl_down(es, o);
  if (lane == 0) red[wv] = es;
  __syncthreads();
  if (t0 == 0)
    atomicAdd(&ws[WS_SUMS + (blockIdx.x & 63)], (red[0] + red[1]) + (red[2] + red[3]));
}

// ---------------- kernel 3: out *= 1/sum -----------------------------------
__global__ __launch_bounds__(256) void k_scale(const float* __restrict__ ws,
                                               float* __restrict__ out) {
  float s = ws[WS_SUMS + (threadIdx.x & 63)];
  #pragma unroll
  for (int o = 1; o < 64; o <<= 1) s += __shfl_xor(s, o);   // identical all lanes
  const float rinv = 1.f / s;
  const int i = blockIdx.x * 256 + threadIdx.x;   // float4 index
  float4 e = ((const float4*)out)[i];
  e.x *= rinv; e.y *= rinv; e.z *= rinv; e.w *= rinv;
  ((float4*)out)[i] = e;
}

extern "C" void kernel_launch(void* const* d_in, const int* in_sizes, int n_in,
                              void* d_out, int out_size, void* d_ws, size_t ws_size,
                              hipStream_t stream) {
  const float* x     = (const float*)d_in[0];
  const float* gum   = (const float*)d_in[1];
  const float* W_s1  = (const float*)d_in[2];
  const float* b_s1  = (const float*)d_in[3];
  const float* W_ih1 = (const float*)d_in[4];
  const float* W_hh1 = (const float*)d_in[5];
  const float* b_ih1 = (const float*)d_in[6];
  const float* b_hh1 = (const float*)d_in[7];
  const float* W_p   = (const float*)d_in[8];
  const float* b_p   = (const float*)d_in[9];
  const float* W_ih2 = (const float*)d_in[10];
  const float* W_hh2 = (const float*)d_in[11];
  const float* b_ih2 = (const float*)d_in[12];
  const float* b_hh2 = (const float*)d_in[13];
  const float* W_r   = (const float*)d_in[14];
  const float* b_r   = (const float*)d_in[15];
  float* ws  = (float*)d_ws;
  float* out = (float*)d_out;

  // zero flags / mflag / sum slots (ws re-poisoned 0xAA before every launch)
  (void)hipMemsetAsync(d_ws, 0, 768, stream);
  k_sender<<<KS + 1,   512, 0, stream>>>(x, W_s1, b_s1, gum, W_ih1, W_hh1,
                                         b_ih1, b_hh1, W_p, b_p,
                                         W_ih2, W_hh2, b_ih2, b_hh2, ws);
  k_out   <<<NCLS/64,  256, 0, stream>>>(W_r, b_r, ws, out);
  k_scale <<<NCLS/1024,256, 0, stream>>>(ws, out);
}